// Round 2
// baseline (559.889 us; speedup 1.0000x reference)
//
#include <hip/hip_runtime.h>
#include <hip/hip_bf16.h>
#include <stdint.h>

#define B_ 4
#define T_ 512
#define V_ 32000
#define D_ 768
#define DH_ 768
#define H_ 4
#define R_ 2048  // B_*T_

typedef unsigned short u16;
typedef __attribute__((ext_vector_type(4))) float f32x4;
typedef __attribute__((ext_vector_type(8))) short s16x8;
typedef __attribute__((address_space(3))) char* lds_cp;
typedef const __attribute__((address_space(1))) char* gl_cp;

__device__ __forceinline__ float bf2f(u16 u){
  union { float f; unsigned int i; } w; w.i = ((unsigned int)u) << 16; return w.f;
}
__device__ __forceinline__ u16 f2bf(float f){
  union { float f; unsigned int i; } w; w.f = f;
  unsigned int r = w.i + 0x7fffu + ((w.i >> 16) & 1u);
  return (u16)(r >> 16);
}

// ---------------- block reductions (256-thread blocks, 4 waves) -------------
__device__ __forceinline__ float block_sum(float v, float* red){
  #pragma unroll
  for (int o = 32; o; o >>= 1) v += __shfl_down(v, o);
  __syncthreads();
  if ((threadIdx.x & 63) == 0) red[threadIdx.x >> 6] = v;
  __syncthreads();
  return red[0] + red[1] + red[2] + red[3];
}
__device__ __forceinline__ float block_max(float v, float* red){
  #pragma unroll
  for (int o = 32; o; o >>= 1) v = fmaxf(v, __shfl_down(v, o));
  __syncthreads();
  if ((threadIdx.x & 63) == 0) red[threadIdx.x >> 6] = v;
  __syncthreads();
  return fmaxf(fmaxf(red[0], red[1]), fmaxf(red[2], red[3]));
}

// ---------------- mask normalize (bool-u8 vs int32 autodetect) --------------
__global__ void mask_convert(const void* __restrict__ mraw, int* __restrict__ mout){
  __shared__ int isbyte;
  if (threadIdx.x == 0) isbyte = 0;
  __syncthreads();
  const unsigned char* by = (const unsigned char*)mraw;
  int f = 0;
  for (int i = threadIdx.x; i < 2048; i += 256)
    if ((i & 3) && by[i]) f = 1;
  if (f) atomicOr(&isbyte, 1);
  __syncthreads();
  if (isbyte){
    for (int i = threadIdx.x; i < 2048; i += 256) mout[i] = by[i] ? 1 : 0;
  } else {
    const int* mi = (const int*)mraw;
    for (int i = threadIdx.x; i < 2048; i += 256) mout[i] = mi[i] ? 1 : 0;
  }
}

// ------- f32 -> bf16 transpose: in f32 [z][R][C] -> out bf16 [z][C][R] ------
__global__ __launch_bounds__(256)
void transpose_f2b(const float* __restrict__ in, u16* __restrict__ out, int R, int C){
  __shared__ u16 tile[32][33];
  long z = blockIdx.z;
  const float* inz = in + z * (long)R * C;
  u16* outz = out + z * (long)R * C;
  int c0 = blockIdx.x * 32, r0 = blockIdx.y * 32;
  int tx = threadIdx.x & 31, ty = threadIdx.x >> 5;
  #pragma unroll
  for (int i = 0; i < 32; i += 8)
    tile[ty + i][tx] = f2bf(inz[(long)(r0 + ty + i) * C + (c0 + tx)]);
  __syncthreads();
  #pragma unroll
  for (int i = 0; i < 32; i += 8)
    outz[(long)(c0 + ty + i) * R + (r0 + tx)] = tile[tx][ty + i];
}

// ---------------- embedding + PE + LayerNorm (f32 in, bf16 out) -------------
__global__ __launch_bounds__(256)
void embed_ln(const int* __restrict__ x, const float* __restrict__ tok,
              const float* __restrict__ seg, const float* __restrict__ g,
              const float* __restrict__ bb, u16* __restrict__ emb){
  __shared__ float red[4];
  int r = blockIdx.x, t = r & 511;
  int tid = threadIdx.x;
  long trow = (long)x[r] * D_;
  long srow = (t > 256) ? (long)D_ : 0;   // seg=1 for t >= T/2+1
  float v[3];
  float s = 0.f;
  #pragma unroll
  for (int q = 0; q < 3; ++q){
    int j = tid + q * 256;
    float d = (2.0f * (float)j) * (1.0f / 768.0f);
    float p = (float)t * powf(10000.0f, -d);
    float pe = (j & 1) ? cosf(p) : sinf(p);
    v[q] = tok[trow + j] + seg[srow + j] + pe;
    s += v[q];
  }
  float mean = block_sum(s, red) * (1.0f / 768.0f);
  float vs = 0.f;
  #pragma unroll
  for (int q = 0; q < 3; ++q){ float dd = v[q] - mean; vs += dd * dd; }
  float var = block_sum(vs, red) * (1.0f / 768.0f);
  float inv = rsqrtf(var + 1e-5f);
  #pragma unroll
  for (int q = 0; q < 3; ++q){
    int j = tid + q * 256;
    emb[(long)r * D_ + j] = f2bf((v[q] - mean) * inv * g[j] + bb[j]);
  }
}

// ---------------- LayerNorm over rows of bf16 [R][768], f32 params ----------
__global__ __launch_bounds__(256)
void ln_rows(const u16* __restrict__ in, const float* __restrict__ g,
             const float* __restrict__ bb, u16* __restrict__ out){
  __shared__ float red[4];
  long r = blockIdx.x;
  int tid = threadIdx.x;
  const u16* row = in + r * D_;
  float v[3];
  float s = 0.f;
  #pragma unroll
  for (int q = 0; q < 3; ++q){ v[q] = bf2f(row[tid + q * 256]); s += v[q]; }
  float mean = block_sum(s, red) * (1.0f / 768.0f);
  float vs = 0.f;
  #pragma unroll
  for (int q = 0; q < 3; ++q){ float dd = v[q] - mean; vs += dd * dd; }
  float var = block_sum(vs, red) * (1.0f / 768.0f);
  float inv = rsqrtf(var + 1e-5f);
  #pragma unroll
  for (int q = 0; q < 3; ++q){
    int j = tid + q * 256;
    out[r * D_ + j] = f2bf((v[q] - mean) * inv * g[j] + bb[j]);
  }
}

// ---------------- attention softmax over S rows (mask fill 1e-9) ------------
__global__ __launch_bounds__(256)
void attn_softmax(u16* __restrict__ S, const int* __restrict__ mask){
  __shared__ float red[4];
  int t = blockIdx.x, z = blockIdx.y, b = z >> 2;
  u16* row = S + (long)z * (T_ * T_) + (long)t * T_;
  int tid = threadIdx.x;
  int s0 = tid, s1 = tid + 256;
  float v0 = mask[b * T_ + s0] ? 1e-9f : bf2f(row[s0]);
  float v1 = mask[b * T_ + s1] ? 1e-9f : bf2f(row[s1]);
  float mx = block_max(fmaxf(v0, v1), red);
  float e0 = expf(v0 - mx), e1 = expf(v1 - mx);
  float l = block_sum(e0 + e1, red);
  float inv = 1.0f / l;
  row[s0] = f2bf(e0 * inv);
  row[s1] = f2bf(e1 * inv);
}

// -------- log-softmax over f32 vocab rows, in-place, online max+sum ---------
__global__ __launch_bounds__(256)
void log_softmax_rows(float* __restrict__ tp){
  __shared__ float sm[256], sl[256];
  long r = blockIdx.x;
  float* row = tp + r * (long)V_;
  f32x4* rv = (f32x4*)row;
  int tid = threadIdx.x;
  float m = -1e30f, l = 0.f;
  for (int c = tid; c < V_ / 4; c += 256){
    f32x4 v = rv[c];
    #pragma unroll
    for (int j = 0; j < 4; ++j){
      float x = v[j];
      if (x > m){ l = l * expf(m - x) + 1.0f; m = x; }
      else l += expf(x - m);
    }
  }
  sm[tid] = m; sl[tid] = l;
  __syncthreads();
  #pragma unroll
  for (int s = 128; s; s >>= 1){
    if (tid < s){
      float m2 = sm[tid + s], l2 = sl[tid + s];
      float M = fmaxf(sm[tid], m2);
      sl[tid] = sl[tid] * expf(sm[tid] - M) + l2 * expf(m2 - M);
      sm[tid] = M;
    }
    __syncthreads();
  }
  float lse = sm[0] + logf(sl[0]);
  for (int c = tid; c < V_ / 4; c += 256){
    f32x4 v = rv[c];
    #pragma unroll
    for (int j = 0; j < 4; ++j) v[j] -= lse;
    rv[c] = v;
  }
}

// ---------------- classifier head (enc bf16, Wc/bc f32, out f32) ------------
__global__ __launch_bounds__(256)
void cls_head(const u16* __restrict__ enc, const float* __restrict__ Wc,
              const float* __restrict__ bc, float* __restrict__ out){
  int w = threadIdx.x >> 6, lane = threadIdx.x & 63;  // w = batch index
  const u16* e = enc + (long)w * (T_ * D_);           // row t=0 of batch w
  float a0 = 0.f, a1 = 0.f;
  for (int k = lane; k < D_; k += 64){
    float ev = bf2f(e[k]);
    a0 += ev * Wc[k * 2 + 0];
    a1 += ev * Wc[k * 2 + 1];
  }
  #pragma unroll
  for (int o = 32; o; o >>= 1){ a0 += __shfl_down(a0, o); a1 += __shfl_down(a1, o); }
  if (lane == 0){
    out[(long)B_ * T_ * V_ + w * 2 + 0] = a0 + bc[0];
    out[(long)B_ * T_ * V_ + w * 2 + 1] = a1 + bc[1];
  }
}

// ---------------- generic MFMA GEMM:  C = A[M,K] * Bt[N,K]^T  ---------------
// 128x128 tile, BK=64, 256 threads (4 waves 2x2), 16x16x32 bf16 MFMA.
// global_load_lds(16B) with XOR-swizzled source; ds_read_b128 with matching
// swizzle. 2-phase prefetch, one barrier per K-tile. Batched pointers:
// z = blockIdx.z; zb=z>>zsh, zh=z&((1<<zsh)-1). C addr = zb*sCzb + zh*sCzh +
// (row>>9)*sCb + (row&511)*sCr + col*sCc. Bias is f32. F32OUT: C is float*.
template<int GELU, int F32OUT>
__global__ __launch_bounds__(256, 2)
void gemm_bt(const u16* __restrict__ A, const u16* __restrict__ Bt,
             const float* __restrict__ bias, void* __restrict__ Cv,
             int lda, int ldb,
             long sAzb, long sAzh, long sBzb, long sBzh, long sbz,
             long sCzb, long sCzh, long sCb, long sCr, long sCc,
             int zsh, float scale, int nt){
  extern __shared__ char smem[];
  u16* sA = (u16*)smem;          // [2][128][64] elements
  u16* sB = sA + 2 * 128 * 64;   // [2][128][64]
  int tid = threadIdx.x, lane = tid & 63, wid = tid >> 6;
  int wm = wid >> 1, wn = wid & 1;
  int lrow = lane & 15, lquad = lane >> 4;
  int z = blockIdx.z, zb = z >> zsh, zh = z & ((1 << zsh) - 1);
  long bm = (long)blockIdx.x * 128, bn = (long)blockIdx.y * 128;
  const u16* Az = A + zb * sAzb + zh * sAzh;
  const u16* Bz = Bt + zb * sBzb + zh * sBzh;

  f32x4 acc[4][4] = {};

  auto stage = [&](int buf, int kt){
    #pragma unroll
    for (int q = 0; q < 4; ++q){
      int seg = wid * 4 + q;
      int idx = seg * 64 + lane;
      int r = idx >> 3, c = idx & 7;
      int ksw = (c ^ (r & 7)) << 3;   // pre-swizzled source chunk
      const u16* srcA = Az + (bm + r) * lda + kt * 64 + ksw;
      const u16* srcB = Bz + (bn + r) * ldb + kt * 64 + ksw;
      __builtin_amdgcn_global_load_lds((gl_cp)srcA,
          (lds_cp)((char*)(sA + buf * 8192) + seg * 1024), 16, 0, 0);
      __builtin_amdgcn_global_load_lds((gl_cp)srcB,
          (lds_cp)((char*)(sB + buf * 8192) + seg * 1024), 16, 0, 0);
    }
  };

  stage(0, 0);
  __syncthreads();
  int cur = 0;
  for (int t = 0; t < nt; ++t){
    if (t + 1 < nt) stage(cur ^ 1, t + 1);
    const u16* a0 = sA + cur * 8192;
    const u16* b0 = sB + cur * 8192;
    #pragma unroll
    for (int kk = 0; kk < 2; ++kk){
      int koff = (((kk * 4 + lquad) ^ (lrow & 7)) << 3);
      s16x8 af[4], bfv[4];
      #pragma unroll
      for (int m = 0; m < 4; ++m)
        af[m] = *(const s16x8*)(a0 + (wm * 64 + m * 16 + lrow) * 64 + koff);
      #pragma unroll
      for (int n = 0; n < 4; ++n)
        bfv[n] = *(const s16x8*)(b0 + (wn * 64 + n * 16 + lrow) * 64 + koff);
      #pragma unroll
      for (int m = 0; m < 4; ++m)
        #pragma unroll
        for (int n = 0; n < 4; ++n)
          acc[m][n] = __builtin_amdgcn_mfma_f32_16x16x32_bf16(af[m], bfv[n], acc[m][n], 0, 0, 0);
    }
    __syncthreads();
    cur ^= 1;
  }

  long czbase = zb * sCzb + zh * sCzh;
  #pragma unroll
  for (int n = 0; n < 4; ++n){
    long col = bn + wn * 64 + n * 16 + lrow;
    float bv = bias ? bias[zb * sbz + col] : 0.f;
    #pragma unroll
    for (int m = 0; m < 4; ++m){
      #pragma unroll
      for (int j = 0; j < 4; ++j){
        long row = bm + wm * 64 + m * 16 + lquad * 4 + j;
        float v = acc[m][n][j] * scale + bv;
        if (GELU) v = 0.5f * v * (1.0f + erff(v * 0.70710678118654752f));
        long ci = czbase + (row >> 9) * sCb + (row & 511) * sCr + col * sCc;
        if (F32OUT) ((float*)Cv)[ci] = v;
        else        ((u16*)Cv)[ci] = f2bf(v);
      }
    }
  }
}

// ---------------------------------------------------------------------------
extern "C" void kernel_launch(void* const* d_in, const int* in_sizes, int n_in,
                              void* d_out, int out_size, void* d_ws, size_t ws_size,
                              hipStream_t stream){
  const int*   x     = (const int*)d_in[0];
  const void*  amask = d_in[1];
  const float* tok = (const float*)d_in[2];
  const float* seg = (const float*)d_in[3];
  const float* lng = (const float*)d_in[4];
  const float* lnb = (const float*)d_in[5];
  const float* Wq  = (const float*)d_in[6];
  const float* bq  = (const float*)d_in[7];
  const float* Wk  = (const float*)d_in[8];
  const float* bk  = (const float*)d_in[9];
  const float* Wv  = (const float*)d_in[10];
  const float* bv  = (const float*)d_in[11];
  const float* Wo  = (const float*)d_in[12];
  const float* bo  = (const float*)d_in[13];
  const float* lag = (const float*)d_in[14];
  const float* lab = (const float*)d_in[15];
  const float* W1  = (const float*)d_in[16];
  const float* b1  = (const float*)d_in[17];
  const float* W2  = (const float*)d_in[18];
  const float* b2  = (const float*)d_in[19];
  const float* leg = (const float*)d_in[20];
  const float* leb = (const float*)d_in[21];
  const float* Wp  = (const float*)d_in[22];
  const float* bp  = (const float*)d_in[23];
  const float* Wc  = (const float*)d_in[24];
  const float* bc  = (const float*)d_in[25];
  float* out = (float*)d_out;
  char* ws = (char*)d_ws;

  size_t off = 0;
  auto alloc = [&](size_t bytes){ size_t o = off; off += (bytes + 255) & ~(size_t)255; return o; };
  size_t o_mask = alloc(2048 * 4);
  size_t o_emb  = alloc((size_t)R_ * D_ * 2);
  size_t o_wqT  = alloc((size_t)H_ * D_ * DH_ * 2);
  size_t o_wkT  = alloc((size_t)H_ * D_ * DH_ * 2);
  size_t o_wvT  = alloc((size_t)H_ * D_ * DH_ * 2);
  size_t o_woT  = alloc((size_t)3072 * 768 * 2);
  size_t o_w1T  = alloc((size_t)768 * 768 * 2);
  size_t o_w2T  = alloc((size_t)768 * 768 * 2);
  size_t o_Q    = alloc((size_t)B_ * H_ * T_ * DH_ * 2);
  size_t o_K    = alloc((size_t)B_ * H_ * T_ * DH_ * 2);
  size_t o_VT   = alloc((size_t)B_ * H_ * DH_ * T_ * 2);
  size_t o_S    = alloc((size_t)B_ * H_ * T_ * T_ * 2);
  size_t o_cat  = alloc((size_t)R_ * 3072 * 2);
  size_t o_ap   = alloc((size_t)R_ * D_ * 2);
  size_t o_ao   = alloc((size_t)R_ * D_ * 2);
  size_t o_h1   = alloc((size_t)R_ * D_ * 2);
  size_t o_ep   = alloc((size_t)R_ * D_ * 2);
  size_t o_enc  = alloc((size_t)R_ * D_ * 2);
  size_t o_wpT  = o_Q;  // Wproj^T bf16 (49.15MB) aliases dead Q..cat span
  if (ws_size < off) return;

  int* maskI = (int*)(ws + o_mask);
  u16* emb  = (u16*)(ws + o_emb);
  u16* wqT  = (u16*)(ws + o_wqT);
  u16* wkT  = (u16*)(ws + o_wkT);
  u16* wvT  = (u16*)(ws + o_wvT);
  u16* woT  = (u16*)(ws + o_woT);
  u16* w1T  = (u16*)(ws + o_w1T);
  u16* w2T  = (u16*)(ws + o_w2T);
  u16* Qb   = (u16*)(ws + o_Q);
  u16* Kb   = (u16*)(ws + o_K);
  u16* VTb  = (u16*)(ws + o_VT);
  u16* Sb   = (u16*)(ws + o_S);
  u16* catb = (u16*)(ws + o_cat);
  u16* apb  = (u16*)(ws + o_ap);
  u16* aob  = (u16*)(ws + o_ao);
  u16* h1b  = (u16*)(ws + o_h1);
  u16* epb  = (u16*)(ws + o_ep);
  u16* encb = (u16*)(ws + o_enc);
  u16* wpT  = (u16*)(ws + o_wpT);

  const long sQK_zb = (long)H_ * T_ * DH_;   // 1572864
  const long sQK_zh = (long)T_ * DH_;        // 393216

  mask_convert<<<1, 256, 0, stream>>>(amask, maskI);
  transpose_f2b<<<dim3(24, 24, 4), 256, 0, stream>>>(Wq, wqT, 768, 768);
  transpose_f2b<<<dim3(24, 24, 4), 256, 0, stream>>>(Wk, wkT, 768, 768);
  transpose_f2b<<<dim3(24, 24, 4), 256, 0, stream>>>(Wv, wvT, 768, 768);
  transpose_f2b<<<dim3(24, 96, 1), 256, 0, stream>>>(Wo, woT, 3072, 768);
  transpose_f2b<<<dim3(24, 24, 1), 256, 0, stream>>>(W1, w1T, 768, 768);
  transpose_f2b<<<dim3(24, 24, 1), 256, 0, stream>>>(W2, w2T, 768, 768);
  embed_ln<<<R_, 256, 0, stream>>>(x, tok, seg, lng, lnb, emb);

  // Q, K: [2048,768] @ WqT[h]  -> [b][h][t][e]
  gemm_bt<0,0><<<dim3(16, 6, 4), 256, 65536, stream>>>(emb, wqT, bq, Qb,
      768, 768, 0, 0, (long)768 * 768, 0, 768,
      sQK_zh, 0, sQK_zb, 768, 1, 0, 1.0f, 12);
  gemm_bt<0,0><<<dim3(16, 6, 4), 256, 65536, stream>>>(emb, wkT, bk, Kb,
      768, 768, 0, 0, (long)768 * 768, 0, 768,
      sQK_zh, 0, sQK_zb, 768, 1, 0, 1.0f, 12);
  // V written transposed -> VT [b][h][e][t]
  gemm_bt<0,0><<<dim3(16, 6, 4), 256, 65536, stream>>>(emb, wvT, bv, VTb,
      768, 768, 0, 0, (long)768 * 768, 0, 768,
      sQK_zh, 0, sQK_zb, 1, 512, 0, 1.0f, 12);

  // scores S[bh][t][s] = scale * Q K^T   (z = b*4+h)
  gemm_bt<0,0><<<dim3(4, 4, 16), 256, 65536, stream>>>(Qb, Kb, nullptr, Sb,
      768, 768, sQK_zb, sQK_zh, sQK_zb, sQK_zh, 0,
      (long)H_ * T_ * T_, (long)T_ * T_, 0, 512, 1, 2, 0.044194173824159216f, 12);

  attn_softmax<<<dim3(512, 16), 256, 0, stream>>>(Sb, maskI);

  // ctx = P @ V  -> cat[b*512+t][h*768+e]
  gemm_bt<0,0><<<dim3(4, 6, 16), 256, 65536, stream>>>(Sb, VTb, nullptr, catb,
      512, 512, (long)H_ * T_ * T_, (long)T_ * T_, sQK_zb, sQK_zh, 0,
      (long)T_ * 3072, 768, 0, 3072, 1, 2, 1.0f, 8);

  // attn_pre = cat @ Wo + bo
  gemm_bt<0,0><<<dim3(16, 6, 1), 256, 65536, stream>>>(catb, woT, bo, apb,
      3072, 3072, 0, 0, 0, 0, 0,
      0, 0, (long)512 * 768, 768, 1, 0, 1.0f, 48);
  ln_rows<<<R_, 256, 0, stream>>>(apb, lag, lab, aob);

  // h1 = gelu(attn_out @ W1 + b1)
  gemm_bt<1,0><<<dim3(16, 6, 1), 256, 65536, stream>>>(aob, w1T, b1, h1b,
      768, 768, 0, 0, 0, 0, 0,
      0, 0, (long)512 * 768, 768, 1, 0, 1.0f, 12);
  // enc_pre = h1 @ W2 + b2
  gemm_bt<0,0><<<dim3(16, 6, 1), 256, 65536, stream>>>(h1b, w2T, b2, epb,
      768, 768, 0, 0, 0, 0, 0,
      0, 0, (long)512 * 768, 768, 1, 0, 1.0f, 12);
  ln_rows<<<R_, 256, 0, stream>>>(epb, leg, leb, encb);

  // Wproj^T bf16 (attention buffers dead; aliases them)
  transpose_f2b<<<dim3(1000, 24, 1), 256, 0, stream>>>(Wp, wpT, 768, 32000);

  // token_pred -> d_out (f32), then in-place log-softmax
  gemm_bt<0,1><<<dim3(16, 250, 1), 256, 65536, stream>>>(encb, wpT, bp, out,
      768, 768, 0, 0, 0, 0, 0,
      0, 0, (long)512 * V_, V_, 1, 0, 1.0f, 12);
  log_softmax_rows<<<R_, 256, 0, stream>>>(out);
  cls_head<<<1, 256, 0, stream>>>(encb, Wc, bc, out);

  (void)in_sizes; (void)n_in; (void)out_size;
}

// Round 3
// 486.048 us; speedup vs baseline: 1.1519x; 1.1519x over previous
//
#include <hip/hip_runtime.h>
#include <hip/hip_bf16.h>
#include <stdint.h>

#define B_ 4
#define T_ 512
#define V_ 32000
#define D_ 768
#define DH_ 768
#define H_ 4
#define R_ 2048  // B_*T_

typedef unsigned short u16;
typedef __attribute__((ext_vector_type(4))) float f32x4;
typedef __attribute__((ext_vector_type(8))) short s16x8;
typedef __attribute__((ext_vector_type(8))) unsigned short u16x8;
typedef __attribute__((address_space(3))) char* lds_cp;
typedef const __attribute__((address_space(1))) char* gl_cp;

__device__ __forceinline__ float bf2f(u16 u){
  union { float f; unsigned int i; } w; w.i = ((unsigned int)u) << 16; return w.f;
}
__device__ __forceinline__ u16 f2bf(float f){
  union { float f; unsigned int i; } w; w.f = f;
  unsigned int r = w.i + 0x7fffu + ((w.i >> 16) & 1u);
  return (u16)(r >> 16);
}

// ---------------- block reductions (256-thread blocks, 4 waves) -------------
__device__ __forceinline__ float block_sum(float v, float* red){
  #pragma unroll
  for (int o = 32; o; o >>= 1) v += __shfl_down(v, o);
  __syncthreads();
  if ((threadIdx.x & 63) == 0) red[threadIdx.x >> 6] = v;
  __syncthreads();
  return red[0] + red[1] + red[2] + red[3];
}
__device__ __forceinline__ float block_max(float v, float* red){
  #pragma unroll
  for (int o = 32; o; o >>= 1) v = fmaxf(v, __shfl_down(v, o));
  __syncthreads();
  if ((threadIdx.x & 63) == 0) red[threadIdx.x >> 6] = v;
  __syncthreads();
  return fmaxf(fmaxf(red[0], red[1]), fmaxf(red[2], red[3]));
}

// ---------------- mask normalize (bool-u8 vs int32 autodetect) --------------
__global__ void mask_convert(const void* __restrict__ mraw, int* __restrict__ mout){
  __shared__ int isbyte;
  if (threadIdx.x == 0) isbyte = 0;
  __syncthreads();
  const unsigned char* by = (const unsigned char*)mraw;
  int f = 0;
  for (int i = threadIdx.x; i < 2048; i += 256)
    if ((i & 3) && by[i]) f = 1;
  if (f) atomicOr(&isbyte, 1);
  __syncthreads();
  if (isbyte){
    for (int i = threadIdx.x; i < 2048; i += 256) mout[i] = by[i] ? 1 : 0;
  } else {
    const int* mi = (const int*)mraw;
    for (int i = threadIdx.x; i < 2048; i += 256) mout[i] = mi[i] ? 1 : 0;
  }
}

// ------- merged f32->bf16 transposes of the six 768-col weights -------------
// z jobs: 0-3 Wq[h], 4-7 Wk[h], 8-11 Wv[h], 12-15 Wo row-chunks (out ld 3072,
// col offset 768k), 16 W1, 17 W2. Each job transposes a [768][768] block.
__global__ __launch_bounds__(256)
void transpose_all(const float* __restrict__ Wq, const float* __restrict__ Wk,
                   const float* __restrict__ Wv, const float* __restrict__ Wo,
                   const float* __restrict__ W1, const float* __restrict__ W2,
                   u16* __restrict__ wqT, u16* __restrict__ wkT,
                   u16* __restrict__ wvT, u16* __restrict__ woT,
                   u16* __restrict__ w1T, u16* __restrict__ w2T){
  __shared__ u16 tile[32][33];
  int z = blockIdx.z;
  const float* in; u16* out; int out_ld = 768;
  if (z < 4)      { in = Wq + (long)z * 589824;        out = wqT + (long)z * 589824; }
  else if (z < 8) { int k = z - 4;  in = Wk + (long)k * 589824; out = wkT + (long)k * 589824; }
  else if (z < 12){ int k = z - 8;  in = Wv + (long)k * 589824; out = wvT + (long)k * 589824; }
  else if (z < 16){ int k = z - 12; in = Wo + (long)k * 589824; out = woT + (long)k * 768; out_ld = 3072; }
  else if (z == 16){ in = W1; out = w1T; }
  else             { in = W2; out = w2T; }
  int c0 = blockIdx.x * 32, r0 = blockIdx.y * 32;
  int tx = threadIdx.x & 31, ty = threadIdx.x >> 5;
  #pragma unroll
  for (int i = 0; i < 32; i += 8)
    tile[ty + i][tx] = f2bf(in[(long)(r0 + ty + i) * 768 + (c0 + tx)]);
  __syncthreads();
  #pragma unroll
  for (int i = 0; i < 32; i += 8)
    out[(long)(c0 + ty + i) * out_ld + (r0 + tx)] = tile[tx][ty + i];
}

// ------- f32 -> bf16 transpose: in f32 [R][C] -> out bf16 [C][R]  (Wproj) ---
__global__ __launch_bounds__(256)
void transpose_f2b(const float* __restrict__ in, u16* __restrict__ out, int R, int C){
  __shared__ u16 tile[32][33];
  int c0 = blockIdx.x * 32, r0 = blockIdx.y * 32;
  int tx = threadIdx.x & 31, ty = threadIdx.x >> 5;
  #pragma unroll
  for (int i = 0; i < 32; i += 8)
    tile[ty + i][tx] = f2bf(in[(long)(r0 + ty + i) * C + (c0 + tx)]);
  __syncthreads();
  #pragma unroll
  for (int i = 0; i < 32; i += 8)
    out[(long)(c0 + ty + i) * R + (r0 + tx)] = tile[tx][ty + i];
}

// ---------------- embedding + PE + LayerNorm (f32 in, bf16 out) -------------
__global__ __launch_bounds__(256)
void embed_ln(const int* __restrict__ x, const float* __restrict__ tok,
              const float* __restrict__ seg, const float* __restrict__ g,
              const float* __restrict__ bb, u16* __restrict__ emb){
  __shared__ float red[4];
  int r = blockIdx.x, t = r & 511;
  int tid = threadIdx.x;
  long trow = (long)x[r] * D_;
  long srow = (t > 256) ? (long)D_ : 0;   // seg=1 for t >= T/2+1
  float v[3];
  float s = 0.f;
  #pragma unroll
  for (int q = 0; q < 3; ++q){
    int j = tid + q * 256;
    float d = (2.0f * (float)j) * (1.0f / 768.0f);
    float p = (float)t * powf(10000.0f, -d);
    float pe = (j & 1) ? cosf(p) : sinf(p);
    v[q] = tok[trow + j] + seg[srow + j] + pe;
    s += v[q];
  }
  float mean = block_sum(s, red) * (1.0f / 768.0f);
  float vs = 0.f;
  #pragma unroll
  for (int q = 0; q < 3; ++q){ float dd = v[q] - mean; vs += dd * dd; }
  float var = block_sum(vs, red) * (1.0f / 768.0f);
  float inv = rsqrtf(var + 1e-5f);
  #pragma unroll
  for (int q = 0; q < 3; ++q){
    int j = tid + q * 256;
    emb[(long)r * D_ + j] = f2bf((v[q] - mean) * inv * g[j] + bb[j]);
  }
}

// ---------------- LayerNorm over rows of bf16 [R][768], f32 params ----------
__global__ __launch_bounds__(256)
void ln_rows(const u16* __restrict__ in, const float* __restrict__ g,
             const float* __restrict__ bb, u16* __restrict__ out){
  __shared__ float red[4];
  long r = blockIdx.x;
  int tid = threadIdx.x;
  const u16* row = in + r * D_;
  float v[3];
  float s = 0.f;
  #pragma unroll
  for (int q = 0; q < 3; ++q){ v[q] = bf2f(row[tid + q * 256]); s += v[q]; }
  float mean = block_sum(s, red) * (1.0f / 768.0f);
  float vs = 0.f;
  #pragma unroll
  for (int q = 0; q < 3; ++q){ float dd = v[q] - mean; vs += dd * dd; }
  float var = block_sum(vs, red) * (1.0f / 768.0f);
  float inv = rsqrtf(var + 1e-5f);
  #pragma unroll
  for (int q = 0; q < 3; ++q){
    int j = tid + q * 256;
    out[r * D_ + j] = f2bf((v[q] - mean) * inv * g[j] + bb[j]);
  }
}

// ---------------- attention softmax over S rows (mask fill 1e-9) ------------
__global__ __launch_bounds__(256)
void attn_softmax(u16* __restrict__ S, const int* __restrict__ mask){
  __shared__ float red[4];
  int t = blockIdx.x, z = blockIdx.y, b = z >> 2;
  u16* row = S + (long)z * (T_ * T_) + (long)t * T_;
  int tid = threadIdx.x;
  int s0 = tid, s1 = tid + 256;
  float v0 = mask[b * T_ + s0] ? 1e-9f : bf2f(row[s0]);
  float v1 = mask[b * T_ + s1] ? 1e-9f : bf2f(row[s1]);
  float mx = block_max(fmaxf(v0, v1), red);
  float e0 = expf(v0 - mx), e1 = expf(v1 - mx);
  float l = block_sum(e0 + e1, red);
  float inv = 1.0f / l;
  row[s0] = f2bf(e0 * inv);
  row[s1] = f2bf(e1 * inv);
}

// -------- log-softmax: bf16 pred row -> f32 out row (2 passes, L2-hot) ------
__global__ __launch_bounds__(256)
void lsm_b2f(const u16* __restrict__ pred, float* __restrict__ out){
  __shared__ float sm[256], sl[256];
  long r = blockIdx.x;
  const u16x8* rv = (const u16x8*)(pred + r * (long)V_);
  int tid = threadIdx.x;
  float m = -1e30f, l = 0.f;
  for (int c = tid; c < V_ / 8; c += 256){
    u16x8 v = rv[c];
    #pragma unroll
    for (int j = 0; j < 8; ++j){
      float x = bf2f(v[j]);
      if (x > m){ l = l * expf(m - x) + 1.0f; m = x; }
      else l += expf(x - m);
    }
  }
  sm[tid] = m; sl[tid] = l;
  __syncthreads();
  #pragma unroll
  for (int s = 128; s; s >>= 1){
    if (tid < s){
      float m2 = sm[tid + s], l2 = sl[tid + s];
      float M = fmaxf(sm[tid], m2);
      sl[tid] = sl[tid] * expf(sm[tid] - M) + l2 * expf(m2 - M);
      sm[tid] = M;
    }
    __syncthreads();
  }
  float lse = sm[0] + logf(sl[0]);
  f32x4* orow = (f32x4*)(out + r * (long)V_);
  for (int c = tid; c < V_ / 8; c += 256){
    u16x8 v = rv[c];
    f32x4 o0, o1;
    #pragma unroll
    for (int j = 0; j < 4; ++j){ o0[j] = bf2f(v[j]) - lse; o1[j] = bf2f(v[j + 4]) - lse; }
    orow[2 * c] = o0; orow[2 * c + 1] = o1;
  }
}

// -------- fallback: log-softmax over f32 vocab rows, in-place ---------------
__global__ __launch_bounds__(256)
void log_softmax_rows(float* __restrict__ tp){
  __shared__ float sm[256], sl[256];
  long r = blockIdx.x;
  float* row = tp + r * (long)V_;
  f32x4* rv = (f32x4*)row;
  int tid = threadIdx.x;
  float m = -1e30f, l = 0.f;
  for (int c = tid; c < V_ / 4; c += 256){
    f32x4 v = rv[c];
    #pragma unroll
    for (int j = 0; j < 4; ++j){
      float x = v[j];
      if (x > m){ l = l * expf(m - x) + 1.0f; m = x; }
      else l += expf(x - m);
    }
  }
  sm[tid] = m; sl[tid] = l;
  __syncthreads();
  #pragma unroll
  for (int s = 128; s; s >>= 1){
    if (tid < s){
      float m2 = sm[tid + s], l2 = sl[tid + s];
      float M = fmaxf(sm[tid], m2);
      sl[tid] = sl[tid] * expf(sm[tid] - M) + l2 * expf(m2 - M);
      sm[tid] = M;
    }
    __syncthreads();
  }
  float lse = sm[0] + logf(sl[0]);
  for (int c = tid; c < V_ / 4; c += 256){
    f32x4 v = rv[c];
    #pragma unroll
    for (int j = 0; j < 4; ++j) v[j] -= lse;
    rv[c] = v;
  }
}

// ---------------- classifier head (enc bf16, Wc/bc f32, out f32) ------------
__global__ __launch_bounds__(256)
void cls_head(const u16* __restrict__ enc, const float* __restrict__ Wc,
              const float* __restrict__ bc, float* __restrict__ out){
  int w = threadIdx.x >> 6, lane = threadIdx.x & 63;  // w = batch index
  const u16* e = enc + (long)w * (T_ * D_);           // row t=0 of batch w
  float a0 = 0.f, a1 = 0.f;
  for (int k = lane; k < D_; k += 64){
    float ev = bf2f(e[k]);
    a0 += ev * Wc[k * 2 + 0];
    a1 += ev * Wc[k * 2 + 1];
  }
  #pragma unroll
  for (int o = 32; o; o >>= 1){ a0 += __shfl_down(a0, o); a1 += __shfl_down(a1, o); }
  if (lane == 0){
    out[(long)B_ * T_ * V_ + w * 2 + 0] = a0 + bc[0];
    out[(long)B_ * T_ * V_ + w * 2 + 1] = a1 + bc[1];
  }
}

// ---------------- generic MFMA GEMM:  C = A[M,K] * Bt[N,K]^T  ---------------
// 128x128 tile, BK=64, 256 threads (4 waves 2x2), 16x16x32 bf16 MFMA.
// global_load_lds(16B) with XOR-swizzled source; ds_read_b128 with matching
// swizzle. 2-phase prefetch, one barrier per K-tile. XCD-aware bijective
// block swizzle (m204) on the flattened grid id for L2 panel locality.
// Batched pointers: zb=z>>zsh, zh=z&((1<<zsh)-1). C addr = zb*sCzb + zh*sCzh +
// (row>>9)*sCb + (row&511)*sCr + col*sCc. Bias is f32. F32OUT: C is float*.
template<int GELU, int F32OUT>
__global__ __launch_bounds__(256, 2)
void gemm_bt(const u16* __restrict__ A, const u16* __restrict__ Bt,
             const float* __restrict__ bias, void* __restrict__ Cv,
             int lda, int ldb,
             long sAzb, long sAzh, long sBzb, long sBzh, long sbz,
             long sCzb, long sCzh, long sCb, long sCr, long sCc,
             int zsh, float scale, int nt){
  extern __shared__ char smem[];
  u16* sA = (u16*)smem;          // [2][128][64] elements
  u16* sB = sA + 2 * 128 * 64;   // [2][128][64]
  int tid = threadIdx.x, lane = tid & 63, wid = tid >> 6;
  int wm = wid >> 1, wn = wid & 1;
  int lrow = lane & 15, lquad = lane >> 4;

  // XCD-aware bijective swizzle (T1, m204)
  unsigned gx = gridDim.x, gy = gridDim.y;
  unsigned nwg = gx * gy * gridDim.z;
  unsigned id = blockIdx.x + gx * (blockIdx.y + gy * blockIdx.z);
  unsigned qq = nwg >> 3, rr = nwg & 7, xcd = id & 7, loc = id >> 3;
  unsigned nid = (xcd < rr ? xcd * (qq + 1) : rr * (qq + 1) + (xcd - rr) * qq) + loc;
  unsigned bx = nid % gx, tmpq = nid / gx;
  unsigned by = tmpq % gy, bz = tmpq / gy;

  int z = (int)bz, zb = z >> zsh, zh = z & ((1 << zsh) - 1);
  long bm = (long)bx * 128, bn = (long)by * 128;
  const u16* Az = A + zb * sAzb + zh * sAzh;
  const u16* Bz = Bt + zb * sBzb + zh * sBzh;

  f32x4 acc[4][4] = {};

  auto stage = [&](int buf, int kt){
    #pragma unroll
    for (int q = 0; q < 4; ++q){
      int seg = wid * 4 + q;
      int idx = seg * 64 + lane;
      int r = idx >> 3, c = idx & 7;
      int ksw = (c ^ (r & 7)) << 3;   // pre-swizzled source chunk
      const u16* srcA = Az + (bm + r) * lda + kt * 64 + ksw;
      const u16* srcB = Bz + (bn + r) * ldb + kt * 64 + ksw;
      __builtin_amdgcn_global_load_lds((gl_cp)srcA,
          (lds_cp)((char*)(sA + buf * 8192) + seg * 1024), 16, 0, 0);
      __builtin_amdgcn_global_load_lds((gl_cp)srcB,
          (lds_cp)((char*)(sB + buf * 8192) + seg * 1024), 16, 0, 0);
    }
  };

  stage(0, 0);
  __syncthreads();
  int cur = 0;
  for (int t = 0; t < nt; ++t){
    if (t + 1 < nt) stage(cur ^ 1, t + 1);
    const u16* a0 = sA + cur * 8192;
    const u16* b0 = sB + cur * 8192;
    #pragma unroll
    for (int kk = 0; kk < 2; ++kk){
      int koff = (((kk * 4 + lquad) ^ (lrow & 7)) << 3);
      s16x8 af[4], bfv[4];
      #pragma unroll
      for (int m = 0; m < 4; ++m)
        af[m] = *(const s16x8*)(a0 + (wm * 64 + m * 16 + lrow) * 64 + koff);
      #pragma unroll
      for (int n = 0; n < 4; ++n)
        bfv[n] = *(const s16x8*)(b0 + (wn * 64 + n * 16 + lrow) * 64 + koff);
      #pragma unroll
      for (int m = 0; m < 4; ++m)
        #pragma unroll
        for (int n = 0; n < 4; ++n)
          acc[m][n] = __builtin_amdgcn_mfma_f32_16x16x32_bf16(af[m], bfv[n], acc[m][n], 0, 0, 0);
    }
    __syncthreads();
    cur ^= 1;
  }

  long czbase = zb * sCzb + zh * sCzh;
  #pragma unroll
  for (int n = 0; n < 4; ++n){
    long col = bn + wn * 64 + n * 16 + lrow;
    float bv = bias ? bias[zb * sbz + col] : 0.f;
    #pragma unroll
    for (int m = 0; m < 4; ++m){
      #pragma unroll
      for (int j = 0; j < 4; ++j){
        long row = bm + wm * 64 + m * 16 + lquad * 4 + j;
        float v = acc[m][n][j] * scale + bv;
        if (GELU) v = 0.5f * v * (1.0f + erff(v * 0.70710678118654752f));
        long ci = czbase + (row >> 9) * sCb + (row & 511) * sCr + col * sCc;
        if (F32OUT) ((float*)Cv)[ci] = v;
        else        ((u16*)Cv)[ci] = f2bf(v);
      }
    }
  }
}

// ---------------------------------------------------------------------------
extern "C" void kernel_launch(void* const* d_in, const int* in_sizes, int n_in,
                              void* d_out, int out_size, void* d_ws, size_t ws_size,
                              hipStream_t stream){
  const int*   x     = (const int*)d_in[0];
  const void*  amask = d_in[1];
  const float* tok = (const float*)d_in[2];
  const float* seg = (const float*)d_in[3];
  const float* lng = (const float*)d_in[4];
  const float* lnb = (const float*)d_in[5];
  const float* Wq  = (const float*)d_in[6];
  const float* bq  = (const float*)d_in[7];
  const float* Wk  = (const float*)d_in[8];
  const float* bk  = (const float*)d_in[9];
  const float* Wv  = (const float*)d_in[10];
  const float* bv  = (const float*)d_in[11];
  const float* Wo  = (const float*)d_in[12];
  const float* bo  = (const float*)d_in[13];
  const float* lag = (const float*)d_in[14];
  const float* lab = (const float*)d_in[15];
  const float* W1  = (const float*)d_in[16];
  const float* b1  = (const float*)d_in[17];
  const float* W2  = (const float*)d_in[18];
  const float* b2  = (const float*)d_in[19];
  const float* leg = (const float*)d_in[20];
  const float* leb = (const float*)d_in[21];
  const float* Wp  = (const float*)d_in[22];
  const float* bp  = (const float*)d_in[23];
  const float* Wc  = (const float*)d_in[24];
  const float* bc  = (const float*)d_in[25];
  float* out = (float*)d_out;
  char* ws = (char*)d_ws;

  size_t off = 0;
  auto alloc = [&](size_t bytes){ size_t o = off; off += (bytes + 255) & ~(size_t)255; return o; };
  size_t o_mask = alloc(2048 * 4);
  size_t o_emb  = alloc((size_t)R_ * D_ * 2);
  size_t o_wqT  = alloc((size_t)H_ * D_ * DH_ * 2);
  size_t o_wkT  = alloc((size_t)H_ * D_ * DH_ * 2);
  size_t o_wvT  = alloc((size_t)H_ * D_ * DH_ * 2);
  size_t o_woT  = alloc((size_t)3072 * 768 * 2);
  size_t o_w1T  = alloc((size_t)768 * 768 * 2);
  size_t o_w2T  = alloc((size_t)768 * 768 * 2);
  size_t o_Q    = alloc((size_t)B_ * H_ * T_ * DH_ * 2);
  size_t o_K    = alloc((size_t)B_ * H_ * T_ * DH_ * 2);
  size_t o_VT   = alloc((size_t)B_ * H_ * DH_ * T_ * 2);
  size_t o_S    = alloc((size_t)B_ * H_ * T_ * T_ * 2);
  size_t o_cat  = alloc((size_t)R_ * 3072 * 2);
  size_t o_ap   = alloc((size_t)R_ * D_ * 2);
  size_t o_ao   = alloc((size_t)R_ * D_ * 2);
  size_t o_h1   = alloc((size_t)R_ * D_ * 2);
  size_t o_ep   = alloc((size_t)R_ * D_ * 2);
  size_t o_enc  = alloc((size_t)R_ * D_ * 2);
  size_t o_wpT  = o_Q;  // Wproj^T bf16 (49.15MB) aliases dead Q..cat span
  size_t off_base = off;
  size_t o_pred = alloc((size_t)R_ * V_ * 2);  // bf16 token_pred (131 MB), optional
  int bigws = (ws_size >= off);
  if (ws_size < off_base) return;

  int* maskI = (int*)(ws + o_mask);
  u16* emb  = (u16*)(ws + o_emb);
  u16* wqT  = (u16*)(ws + o_wqT);
  u16* wkT  = (u16*)(ws + o_wkT);
  u16* wvT  = (u16*)(ws + o_wvT);
  u16* woT  = (u16*)(ws + o_woT);
  u16* w1T  = (u16*)(ws + o_w1T);
  u16* w2T  = (u16*)(ws + o_w2T);
  u16* Qb   = (u16*)(ws + o_Q);
  u16* Kb   = (u16*)(ws + o_K);
  u16* VTb  = (u16*)(ws + o_VT);
  u16* Sb   = (u16*)(ws + o_S);
  u16* catb = (u16*)(ws + o_cat);
  u16* apb  = (u16*)(ws + o_ap);
  u16* aob  = (u16*)(ws + o_ao);
  u16* h1b  = (u16*)(ws + o_h1);
  u16* epb  = (u16*)(ws + o_ep);
  u16* encb = (u16*)(ws + o_enc);
  u16* wpT  = (u16*)(ws + o_wpT);
  u16* predb = (u16*)(ws + o_pred);

  const long sQK_zb = (long)H_ * T_ * DH_;   // 1572864
  const long sQK_zh = (long)T_ * DH_;        // 393216

  mask_convert<<<1, 256, 0, stream>>>(amask, maskI);
  transpose_all<<<dim3(24, 24, 18), 256, 0, stream>>>(Wq, Wk, Wv, Wo, W1, W2,
      wqT, wkT, wvT, woT, w1T, w2T);
  embed_ln<<<R_, 256, 0, stream>>>(x, tok, seg, lng, lnb, emb);

  // Q, K: [2048,768] @ WqT[h]  -> [b][h][t][e]
  gemm_bt<0,0><<<dim3(16, 6, 4), 256, 65536, stream>>>(emb, wqT, bq, Qb,
      768, 768, 0, 0, (long)768 * 768, 0, 768,
      sQK_zh, 0, sQK_zb, 768, 1, 0, 1.0f, 12);
  gemm_bt<0,0><<<dim3(16, 6, 4), 256, 65536, stream>>>(emb, wkT, bk, Kb,
      768, 768, 0, 0, (long)768 * 768, 0, 768,
      sQK_zh, 0, sQK_zb, 768, 1, 0, 1.0f, 12);
  // V written transposed -> VT [b][h][e][t]
  gemm_bt<0,0><<<dim3(16, 6, 4), 256, 65536, stream>>>(emb, wvT, bv, VTb,
      768, 768, 0, 0, (long)768 * 768, 0, 768,
      sQK_zh, 0, sQK_zb, 1, 512, 0, 1.0f, 12);

  // scores S[bh][t][s] = scale * Q K^T   (z = b*4+h)
  gemm_bt<0,0><<<dim3(4, 4, 16), 256, 65536, stream>>>(Qb, Kb, nullptr, Sb,
      768, 768, sQK_zb, sQK_zh, sQK_zb, sQK_zh, 0,
      (long)H_ * T_ * T_, (long)T_ * T_, 0, 512, 1, 2, 0.044194173824159216f, 12);

  attn_softmax<<<dim3(512, 16), 256, 0, stream>>>(Sb, maskI);

  // ctx = P @ V  -> cat[b*512+t][h*768+e]
  gemm_bt<0,0><<<dim3(4, 6, 16), 256, 65536, stream>>>(Sb, VTb, nullptr, catb,
      512, 512, (long)H_ * T_ * T_, (long)T_ * T_, sQK_zb, sQK_zh, 0,
      (long)T_ * 3072, 768, 0, 3072, 1, 2, 1.0f, 8);

  // attn_pre = cat @ Wo + bo
  gemm_bt<0,0><<<dim3(16, 6, 1), 256, 65536, stream>>>(catb, woT, bo, apb,
      3072, 3072, 0, 0, 0, 0, 0,
      0, 0, (long)512 * 768, 768, 1, 0, 1.0f, 48);
  ln_rows<<<R_, 256, 0, stream>>>(apb, lag, lab, aob);

  // h1 = gelu(attn_out @ W1 + b1)
  gemm_bt<1,0><<<dim3(16, 6, 1), 256, 65536, stream>>>(aob, w1T, b1, h1b,
      768, 768, 0, 0, 0, 0, 0,
      0, 0, (long)512 * 768, 768, 1, 0, 1.0f, 12);
  // enc_pre = h1 @ W2 + b2
  gemm_bt<0,0><<<dim3(16, 6, 1), 256, 65536, stream>>>(h1b, w2T, b2, epb,
      768, 768, 0, 0, 0, 0, 0,
      0, 0, (long)512 * 768, 768, 1, 0, 1.0f, 12);
  ln_rows<<<R_, 256, 0, stream>>>(epb, leg, leb, encb);

  // Wproj^T bf16 (attention buffers dead; aliases them)
  transpose_f2b<<<dim3(1000, 24, 1), 256, 0, stream>>>(Wp, wpT, 768, 32000);

  if (bigws){
    // token_pred -> bf16 ws, then fused bf16->f32 log-softmax into d_out
    gemm_bt<0,0><<<dim3(16, 250, 1), 256, 65536, stream>>>(encb, wpT, bp, predb,
        768, 768, 0, 0, 0, 0, 0,
        0, 0, (long)512 * V_, V_, 1, 0, 1.0f, 12);
    lsm_b2f<<<R_, 256, 0, stream>>>(predb, out);
  } else {
    // fallback: f32 direct to d_out + in-place log-softmax
    gemm_bt<0,1><<<dim3(16, 250, 1), 256, 65536, stream>>>(encb, wpT, bp, out,
        768, 768, 0, 0, 0, 0, 0,
        0, 0, (long)512 * V_, V_, 1, 0, 1.0f, 12);
    log_softmax_rows<<<R_, 256, 0, stream>>>(out);
  }
  cls_head<<<1, 256, 0, stream>>>(encb, Wc, bc, out);

  (void)in_sizes; (void)n_in; (void)out_size;
}